// Round 2
// baseline (499.906 us; speedup 1.0000x reference)
//
#include <hip/hip_runtime.h>
#include <hip/hip_bf16.h>

#define M_DIM 8192
#define N_DIM 3072
#define K_DIM 3072
#define RANK_ 64

#define BM 128
#define BN 128
#define BK 32
#define NTILES (K_DIM / BK)

typedef __attribute__((ext_vector_type(8))) __bf16 bf16x8;
typedef __attribute__((ext_vector_type(4))) float floatx4;
typedef __attribute__((ext_vector_type(8))) unsigned short ushort8;

__device__ __forceinline__ unsigned short f2bf(float f) {
  union { float f; unsigned u; } v;
  v.f = f;
  return (unsigned short)((v.u + 0x7fffu + ((v.u >> 16) & 1u)) >> 16);
}

// ---- Kernel 1: x fp32 -> bf16 ----
__global__ void cvt_x_kernel(const float* __restrict__ x, unsigned short* __restrict__ xb) {
  size_t i = ((size_t)blockIdx.x * 256u + threadIdx.x) * 8u;
  const float4* xp = (const float4*)(x + i);
  float4 a = xp[0];
  float4 b = xp[1];
  ushort8 r;
  r[0] = f2bf(a.x); r[1] = f2bf(a.y); r[2] = f2bf(a.z); r[3] = f2bf(a.w);
  r[4] = f2bf(b.x); r[5] = f2bf(b.y); r[6] = f2bf(b.z); r[7] = f2bf(b.w);
  *(ushort8*)(xb + i) = r;
}

// ---- Kernel 2: W_eff[o][i] = Wq[o][i]*scale[o] + sum_r A[o][r]*B[r][i]  (bf16) ----
__global__ void build_weff_kernel(const int* __restrict__ wq, const float* __restrict__ scale,
                                  const float* __restrict__ lA, const float* __restrict__ lB,
                                  unsigned short* __restrict__ weff) {
  __shared__ float sA[RANK_];
  int o = blockIdx.y;
  int i = blockIdx.x * 256 + threadIdx.x;
  if (threadIdx.x < RANK_) sA[threadIdx.x] = lA[(size_t)o * RANK_ + threadIdx.x];
  __syncthreads();
  float acc = (float)wq[(size_t)o * K_DIM + i] * scale[o];
#pragma unroll 16
  for (int r = 0; r < RANK_; ++r) acc += sA[r] * lB[(size_t)r * K_DIM + i];
  weff[(size_t)o * K_DIM + i] = f2bf(acc);
}

// ---- Kernel 3: out[m][o] = sum_k xb[m][k] * weff[o][k] + bias[o] ----
// m97-structure: 128x128 tile, BK=32, 4 waves (2x2), 4x4 frags of 16x16x32 bf16 MFMA,
// global_load_lds width=16 staging, double-buffered LDS, 1 barrier per K-step.
__global__ __launch_bounds__(256) void gemm_kernel(const unsigned short* __restrict__ xb,
                                                   const unsigned short* __restrict__ weff,
                                                   const float* __restrict__ bias,
                                                   float* __restrict__ out) {
  __shared__ alignas(16) unsigned short As[2][BM * BK];
  __shared__ alignas(16) unsigned short Bs[2][BN * BK];

  const int tid = threadIdx.x;
  const int lane = tid & 63;
  const int wid = tid >> 6;
  const int waveRow = wid >> 1;
  const int waveCol = wid & 1;

  // XCD-aware bijective swizzle (nwg = 1536, divisible by 8)
  const int nwg = gridDim.x;
  const int cpx = nwg >> 3;
  const int bid = blockIdx.x;
  const int swz = (bid & 7) * cpx + (bid >> 3);
  const int tileM = swz / (N_DIM / BN);
  const int tileN = swz % (N_DIM / BN);

  const size_t rowA0 = (size_t)tileM * BM;
  const size_t colB0 = (size_t)tileN * BN;

  const int lrow = lane & 15;
  const int lk = (lane >> 4) * 8;

  floatx4 acc[4][4];
#pragma unroll
  for (int m = 0; m < 4; ++m)
#pragma unroll
    for (int n = 0; n < 4; ++n)
      acc[m][n] = (floatx4){0.f, 0.f, 0.f, 0.f};

  const int sr = tid >> 2;        // staging row within 64-row half
  const int sc = (tid & 3) * 8;   // staging col (8 bf16 = 16B)

  auto stage = [&](int t, int buf) {
    size_t k0 = (size_t)t * BK;
#pragma unroll
    for (int j = 0; j < 2; ++j) {
      const unsigned short* gA = xb + (rowA0 + (size_t)(j * 64 + sr)) * K_DIM + k0 + sc;
      unsigned short* lA_ = &As[buf][j * 2048 + tid * 8];
      __builtin_amdgcn_global_load_lds((const __attribute__((address_space(1))) void*)gA,
                                       (__attribute__((address_space(3))) void*)lA_, 16, 0, 0);
      const unsigned short* gB = weff + (colB0 + (size_t)(j * 64 + sr)) * K_DIM + k0 + sc;
      unsigned short* lB_ = &Bs[buf][j * 2048 + tid * 8];
      __builtin_amdgcn_global_load_lds((const __attribute__((address_space(1))) void*)gB,
                                       (__attribute__((address_space(3))) void*)lB_, 16, 0, 0);
    }
  };

  stage(0, 0);
  __syncthreads();

  int cur = 0;
  for (int t = 0; t < NTILES; ++t) {
    if (t + 1 < NTILES) stage(t + 1, cur ^ 1);

    const unsigned short* At = As[cur];
    const unsigned short* Bt = Bs[cur];
    bf16x8 af[4], bfr[4];
#pragma unroll
    for (int m = 0; m < 4; ++m)
      af[m] = *(const bf16x8*)&At[(waveRow * 64 + m * 16 + lrow) * BK + lk];
#pragma unroll
    for (int n = 0; n < 4; ++n)
      bfr[n] = *(const bf16x8*)&Bt[(waveCol * 64 + n * 16 + lrow) * BK + lk];

#pragma unroll
    for (int m = 0; m < 4; ++m)
#pragma unroll
      for (int n = 0; n < 4; ++n)
        acc[m][n] = __builtin_amdgcn_mfma_f32_16x16x32_bf16(af[m], bfr[n], acc[m][n], 0, 0, 0);

    __syncthreads();
    cur ^= 1;
  }

  // Epilogue: C/D layout col=lane&15, row=(lane>>4)*4+reg (m89-verified). Fuse bias.
  const int quad = lane >> 4;
#pragma unroll
  for (int n = 0; n < 4; ++n) {
    int col = (int)colB0 + waveCol * 64 + n * 16 + lrow;
    float bv = bias[col];
#pragma unroll
    for (int m = 0; m < 4; ++m) {
      size_t rbase = rowA0 + (size_t)(waveRow * 64 + m * 16 + quad * 4);
#pragma unroll
      for (int j = 0; j < 4; ++j)
        out[(rbase + j) * N_DIM + col] = acc[m][n][j] + bv;
    }
  }
}

extern "C" void kernel_launch(void* const* d_in, const int* in_sizes, int n_in,
                              void* d_out, int out_size, void* d_ws, size_t ws_size,
                              hipStream_t stream) {
  const float* x = (const float*)d_in[0];
  const int* wq = (const int*)d_in[1];
  const float* scale = (const float*)d_in[2];
  const float* lA = (const float*)d_in[3];
  const float* lB = (const float*)d_in[4];
  const float* bias = (const float*)d_in[5];
  float* out = (float*)d_out;

  unsigned short* xb = (unsigned short*)d_ws;                 // 8192*3072 bf16 = 50.3 MB
  unsigned short* weff = xb + (size_t)M_DIM * K_DIM;          // 3072*3072 bf16 = 18.9 MB

  // x fp32 -> bf16
  cvt_x_kernel<<<(M_DIM * (size_t)K_DIM) / (8 * 256), 256, 0, stream>>>(x, xb);
  // fold ternary*scale + LoRA into bf16 W_eff
  build_weff_kernel<<<dim3(K_DIM / 256, N_DIM), 256, 0, stream>>>(wq, scale, lA, lB, weff);
  // single bf16 GEMM + bias
  gemm_kernel<<<(M_DIM / BM) * (N_DIM / BN), 256, 0, stream>>>(xb, weff, bias, out);
}

// Round 3
// 462.954 us; speedup vs baseline: 1.0798x; 1.0798x over previous
//
#include <hip/hip_runtime.h>
#include <hip/hip_bf16.h>

#define M_DIM 8192
#define N_DIM 3072
#define K_DIM 3072
#define RANK_ 64

#define BM 256
#define BN 256
#define BK 64
#define NT (K_DIM / BK)   // 48 K-tile groups

typedef __attribute__((ext_vector_type(8))) __bf16 bf16x8;
typedef __attribute__((ext_vector_type(4))) float floatx4;
typedef __attribute__((ext_vector_type(8))) unsigned short ushort8;

__device__ __forceinline__ unsigned short f2bf(float f) {
  union { float f; unsigned u; } v;
  v.f = f;
  return (unsigned short)((v.u + 0x7fffu + ((v.u >> 16) & 1u)) >> 16);
}

// ---- Kernel 1: x fp32 -> bf16 (memory-bound, vectorized) ----
__global__ void cvt_x_kernel(const float* __restrict__ x, unsigned short* __restrict__ xb) {
  size_t i = ((size_t)blockIdx.x * 256u + threadIdx.x) * 8u;
  const float4* xp = (const float4*)(x + i);
  float4 a = xp[0];
  float4 b = xp[1];
  ushort8 r;
  r[0] = f2bf(a.x); r[1] = f2bf(a.y); r[2] = f2bf(a.z); r[3] = f2bf(a.w);
  r[4] = f2bf(b.x); r[5] = f2bf(b.y); r[6] = f2bf(b.z); r[7] = f2bf(b.w);
  *(ushort8*)(xb + i) = r;
}

// ---- Kernel 2 v2: W_eff = Wq*scale + A@B, bf16 out ----
// Block = 32 o-rows x 128 i-cols. Each thread: hold all 64 lB values in VGPRs
// (one coalesced pass), lA rows are wave-uniform loads, 16 outputs/thread.
// Kills the 2.4 GB L2 re-read of v1.
__global__ __launch_bounds__(256) void build_weff_kernel(
    const int* __restrict__ wq, const float* __restrict__ scale,
    const float* __restrict__ lA, const float* __restrict__ lB,
    unsigned short* __restrict__ weff) {
  const int tid = threadIdx.x;
  const int i = blockIdx.x * 128 + (tid & 127);
  const int o0 = blockIdx.y * 32 + (tid >> 7) * 16;

  float bv[64];
#pragma unroll
  for (int r = 0; r < 64; ++r) bv[r] = lB[(size_t)r * K_DIM + i];

  float acc[16];
#pragma unroll
  for (int oo = 0; oo < 16; ++oo) {
    const int o = o0 + oo;
    float a = (float)wq[(size_t)o * K_DIM + i] * scale[o];
    const float* __restrict__ Arow = lA + (size_t)o * RANK_;
#pragma unroll
    for (int r = 0; r < 64; ++r) a += Arow[r] * bv[r];
    acc[oo] = a;
  }
#pragma unroll
  for (int oo = 0; oo < 16; ++oo)
    weff[(size_t)(o0 + oo) * K_DIM + i] = f2bf(acc[oo]);
}

// ---- Kernel 3: 256x256 8-phase bf16 GEMM (T1+T2+T3/T4+T5) ----
// 8 waves (2M x 4N), BK=64, 128 KiB LDS (2 dbuf x (A 32K + B 32K)).
// LDS swizzle: element (row,k) stored at ushort idx row*64 + (k ^ ((row&7)<<3));
// global_load_lds dest stays LINEAR, source k is pre-swizzled (rule #21).
// Schedule per group g (4 phases, 16 MFMA each):
//   ph1: ds A(m0-3,kk0)+B(kk0); stage A(g+1)   [dbuf[(g+1)&1] freed at (g-1).ph4]
//   ph2: ds A(m4-7,kk0)        [B regs reused]
//   ph3: ds A(m0-3,kk1)+B(kk1)
//   ph4: ds A(m4-7,kk1); stage B(g+2)          [B-region of dbuf[g&1] retired at ph3]
//        gate: vmcnt(4) -> tile g+1 fully landed (>=3-phase flight per half)
#define MF(A,B,C) __builtin_amdgcn_mfma_f32_16x16x32_bf16(A, B, C, 0, 0, 0)
#define MFMA16(MB) do { \
  acc[MB+0][0]=MF(a0,b0,acc[MB+0][0]); acc[MB+0][1]=MF(a0,b1,acc[MB+0][1]); \
  acc[MB+0][2]=MF(a0,b2,acc[MB+0][2]); acc[MB+0][3]=MF(a0,b3,acc[MB+0][3]); \
  acc[MB+1][0]=MF(a1,b0,acc[MB+1][0]); acc[MB+1][1]=MF(a1,b1,acc[MB+1][1]); \
  acc[MB+1][2]=MF(a1,b2,acc[MB+1][2]); acc[MB+1][3]=MF(a1,b3,acc[MB+1][3]); \
  acc[MB+2][0]=MF(a2,b0,acc[MB+2][0]); acc[MB+2][1]=MF(a2,b1,acc[MB+2][1]); \
  acc[MB+2][2]=MF(a2,b2,acc[MB+2][2]); acc[MB+2][3]=MF(a2,b3,acc[MB+2][3]); \
  acc[MB+3][0]=MF(a3,b0,acc[MB+3][0]); acc[MB+3][1]=MF(a3,b1,acc[MB+3][1]); \
  acc[MB+3][2]=MF(a3,b2,acc[MB+3][2]); acc[MB+3][3]=MF(a3,b3,acc[MB+3][3]); \
} while (0)

__global__ __launch_bounds__(512, 2) void gemm8_kernel(
    const unsigned short* __restrict__ xb, const unsigned short* __restrict__ weff,
    const float* __restrict__ bias, float* __restrict__ out) {
  extern __shared__ unsigned short smem[];  // 65536 ushorts = 128 KiB

  const int tid = threadIdx.x;
  const int lane = tid & 63;
  const int wid = tid >> 6;     // 0..7
  const int wm = wid >> 2;      // 0..1  (M)
  const int wn = wid & 3;       // 0..3  (N)

  // XCD-aware bijective swizzle (384 % 8 == 0)
  const int bid = blockIdx.x;
  const int swz = (bid & 7) * 48 + (bid >> 3);
  const int tileM = swz / (N_DIM / BN);
  const int tileN = swz % (N_DIM / BN);
  const int rowA0 = tileM * BM;
  const int colB0 = tileN * BN;

  // staging: thread -> linear LDS ushort idx tid*8 within a 64-row chunk;
  // decodes to (row = l*64 + tid>>3, col = (tid&7)*8); source k pre-swizzled.
  const int srow = tid >> 3;
  const int skidx = ((tid & 7) * 8) ^ ((srow & 7) << 3);
  const unsigned short* gAbase = xb + (size_t)(rowA0 + srow) * K_DIM + skidx;
  const unsigned short* gBbase = weff + (size_t)(colB0 + srow) * K_DIM + skidx;
  const int ldsLin = tid * 8;

#define ABASE(b) ((b) * 32768)
#define BBASE(b) ((b) * 32768 + 16384)

  auto stageA = [&](int t) {
    const int b = t & 1;
    const unsigned short* g = gAbase + (size_t)t * BK;
#pragma unroll
    for (int l = 0; l < 4; ++l)
      __builtin_amdgcn_global_load_lds(
          (const __attribute__((address_space(1))) void*)(g + (size_t)l * 64 * K_DIM),
          (__attribute__((address_space(3))) void*)&smem[ABASE(b) + l * 4096 + ldsLin], 16, 0, 0);
  };
  auto stageB = [&](int t) {
    const int b = t & 1;
    const unsigned short* g = gBbase + (size_t)t * BK;
#pragma unroll
    for (int l = 0; l < 4; ++l)
      __builtin_amdgcn_global_load_lds(
          (const __attribute__((address_space(1))) void*)(g + (size_t)l * 64 * K_DIM),
          (__attribute__((address_space(3))) void*)&smem[BBASE(b) + l * 4096 + ldsLin], 16, 0, 0);
  };

  // fragment reads (swizzled): row&7 == lrow&7 since bases are multiples of 8
  const int lrow = lane & 15;
  const int khalf = lane >> 4;             // 0..3
  const int rsw = (lrow & 7) << 3;
  auto ldA = [&](int b, int mf, int kk) -> bf16x8 {
    return *(const bf16x8*)&smem[ABASE(b) + (wm * 128 + mf * 16 + lrow) * 64 +
                                 ((kk * 32 + khalf * 8) ^ rsw)];
  };
  auto ldB = [&](int b, int nf, int kk) -> bf16x8 {
    return *(const bf16x8*)&smem[BBASE(b) + (wn * 64 + nf * 16 + lrow) * 64 +
                                 ((kk * 32 + khalf * 8) ^ rsw)];
  };

  floatx4 acc[8][4];
#pragma unroll
  for (int m = 0; m < 8; ++m)
#pragma unroll
    for (int n = 0; n < 4; ++n)
      acc[m][n] = (floatx4){0.f, 0.f, 0.f, 0.f};

  // prologue: B(0), A(0), B(1) staged; gate tile 0 (vmcnt(4) leaves B(1) in flight)
  stageB(0); stageA(0); stageB(1);
  asm volatile("s_waitcnt vmcnt(4)" ::: "memory");
  __builtin_amdgcn_s_barrier();

  bf16x8 a0, a1, a2, a3, b0, b1, b2, b3;
#pragma unroll 2
  for (int g = 0; g < NT; ++g) {
    const int bf = g & 1;
    // ---- phase 1
    a0 = ldA(bf, 0, 0); a1 = ldA(bf, 1, 0); a2 = ldA(bf, 2, 0); a3 = ldA(bf, 3, 0);
    b0 = ldB(bf, 0, 0); b1 = ldB(bf, 1, 0); b2 = ldB(bf, 2, 0); b3 = ldB(bf, 3, 0);
    if (g + 1 < NT) stageA(g + 1);
    __builtin_amdgcn_s_barrier();
    asm volatile("s_waitcnt lgkmcnt(0)" ::: "memory");
    __builtin_amdgcn_s_setprio(1);
    MFMA16(0);
    __builtin_amdgcn_s_setprio(0);
    __builtin_amdgcn_s_barrier();
    // ---- phase 2 (B regs reused)
    a0 = ldA(bf, 4, 0); a1 = ldA(bf, 5, 0); a2 = ldA(bf, 6, 0); a3 = ldA(bf, 7, 0);
    __builtin_amdgcn_s_barrier();
    asm volatile("s_waitcnt lgkmcnt(0)" ::: "memory");
    __builtin_amdgcn_s_setprio(1);
    MFMA16(4);
    __builtin_amdgcn_s_setprio(0);
    __builtin_amdgcn_s_barrier();
    // ---- phase 3
    a0 = ldA(bf, 0, 1); a1 = ldA(bf, 1, 1); a2 = ldA(bf, 2, 1); a3 = ldA(bf, 3, 1);
    b0 = ldB(bf, 0, 1); b1 = ldB(bf, 1, 1); b2 = ldB(bf, 2, 1); b3 = ldB(bf, 3, 1);
    __builtin_amdgcn_s_barrier();
    asm volatile("s_waitcnt lgkmcnt(0)" ::: "memory");
    __builtin_amdgcn_s_setprio(1);
    MFMA16(0);
    __builtin_amdgcn_s_setprio(0);
    __builtin_amdgcn_s_barrier();
    // ---- phase 4 + gate
    a0 = ldA(bf, 4, 1); a1 = ldA(bf, 5, 1); a2 = ldA(bf, 6, 1); a3 = ldA(bf, 7, 1);
    if (g + 2 < NT) stageB(g + 2);
    __builtin_amdgcn_s_barrier();
    asm volatile("s_waitcnt lgkmcnt(0)" ::: "memory");
    __builtin_amdgcn_s_setprio(1);
    MFMA16(4);
    __builtin_amdgcn_s_setprio(0);
    if (g < NT - 2) asm volatile("s_waitcnt vmcnt(4)" ::: "memory");
    else            asm volatile("s_waitcnt vmcnt(0)" ::: "memory");
    __builtin_amdgcn_s_barrier();
  }

  // epilogue: C/D layout col=lane&15, row=(lane>>4)*4+j (m89-verified); fuse bias
  const int orow0 = rowA0 + wm * 128;
  const int ocol0 = colB0 + wn * 64;
#pragma unroll
  for (int nf = 0; nf < 4; ++nf) {
    const int col = ocol0 + nf * 16 + lrow;
    const float bvs = bias[col];
#pragma unroll
    for (int mf = 0; mf < 8; ++mf) {
      const int r0 = orow0 + mf * 16 + khalf * 4;
#pragma unroll
      for (int j = 0; j < 4; ++j)
        out[(size_t)(r0 + j) * N_DIM + col] = acc[mf][nf][j] + bvs;
    }
  }
}

extern "C" void kernel_launch(void* const* d_in, const int* in_sizes, int n_in,
                              void* d_out, int out_size, void* d_ws, size_t ws_size,
                              hipStream_t stream) {
  const float* x = (const float*)d_in[0];
  const int* wq = (const int*)d_in[1];
  const float* scale = (const float*)d_in[2];
  const float* lA = (const float*)d_in[3];
  const float* lB = (const float*)d_in[4];
  const float* bias = (const float*)d_in[5];
  float* out = (float*)d_out;

  unsigned short* xb = (unsigned short*)d_ws;           // 8192*3072 bf16 = 50.3 MB
  unsigned short* weff = xb + (size_t)M_DIM * K_DIM;    // 3072*3072 bf16 = 18.9 MB

  hipFuncSetAttribute((const void*)gemm8_kernel,
                      hipFuncAttributeMaxDynamicSharedMemorySize, 131072);

  cvt_x_kernel<<<(M_DIM * (size_t)K_DIM) / (8 * 256), 256, 0, stream>>>(x, xb);
  build_weff_kernel<<<dim3(K_DIM / 128, N_DIM / 32), 256, 0, stream>>>(wq, scale, lA, lB, weff);
  gemm8_kernel<<<(M_DIM / BM) * (N_DIM / BN), 512, 131072, stream>>>(xb, weff, bias, out);
}

// Round 4
// 383.254 us; speedup vs baseline: 1.3044x; 1.2080x over previous
//
#include <hip/hip_runtime.h>
#include <hip/hip_bf16.h>

#define M_DIM 8192
#define N_DIM 3072
#define K_DIM 3072
#define RANK_ 64

#define BM 256
#define BN 256
#define BK 64
#define NT (K_DIM / BK)   // 48 K-tile groups

typedef __attribute__((ext_vector_type(8))) __bf16 bf16x8;
typedef __attribute__((ext_vector_type(4))) float floatx4;
typedef __attribute__((ext_vector_type(8))) unsigned short ushort8;

__device__ __forceinline__ unsigned short f2bf(float f) {
  union { float f; unsigned u; } v;
  v.f = f;
  return (unsigned short)((v.u + 0x7fffu + ((v.u >> 16) & 1u)) >> 16);
}

// ---- Kernel 1: x fp32 -> bf16 (memory-bound, vectorized) ----
__global__ void cvt_x_kernel(const float* __restrict__ x, unsigned short* __restrict__ xb) {
  size_t i = ((size_t)blockIdx.x * 256u + threadIdx.x) * 8u;
  const float4* xp = (const float4*)(x + i);
  float4 a = xp[0];
  float4 b = xp[1];
  ushort8 r;
  r[0] = f2bf(a.x); r[1] = f2bf(a.y); r[2] = f2bf(a.z); r[3] = f2bf(a.w);
  r[4] = f2bf(b.x); r[5] = f2bf(b.y); r[6] = f2bf(b.z); r[7] = f2bf(b.w);
  *(ushort8*)(xb + i) = r;
}

// ---- Kernel 2 v3: W_eff = Wq*scale + A@B, bf16 out ----
// LDS-tiled, 8x8 register blocking. Block = 128 o-rows x 128 i-cols.
// sB[64][128] (lB tile, 32 KB) + sA[128][65] (lA tile, padded row 65 ->
// the 4 distinct o-broadcast reads land on 4 distinct banks). acc[8][8]=64 VGPR
// -> no spill (v2's bv[64]+acc[16]+1024-deep unroll spilled to scratch).
__global__ __launch_bounds__(256) void build_weff_kernel(
    const int* __restrict__ wq, const float* __restrict__ scale,
    const float* __restrict__ lA, const float* __restrict__ lB,
    unsigned short* __restrict__ weff) {
  __shared__ float sB[64][128];
  __shared__ float sA[128][65];

  const int tid = threadIdx.x;
  const int i0 = blockIdx.x * 128;
  const int o0 = blockIdx.y * 128;

  // stage sB: 64x128 f32, coalesced float4 (32 float4 per row, 8 per thread)
#pragma unroll
  for (int l = 0; l < 8; ++l) {
    int lin = l * 256 + tid;
    int r = lin >> 5;
    int c4 = (lin & 31) * 4;
    *(float4*)&sB[r][c4] = *(const float4*)&lB[(size_t)r * K_DIM + i0 + c4];
  }
  // stage sA: 128x64 f32 (16 float4 per row, 8 per thread)
#pragma unroll
  for (int l = 0; l < 8; ++l) {
    int lin = l * 256 + tid;
    int o = lin >> 4;
    int c4 = (lin & 15) * 4;
    *(float4*)&sA[o][c4] = *(const float4*)&lA[(size_t)(o0 + o) * RANK_ + c4];
  }
  __syncthreads();

  const int ith = tid & 15;          // i-group
  const int oth = tid >> 4;          // o-group
  const int ib = ith * 8;
  const int ob = oth * 8;

  float acc[8][8];
  // init: acc = wq * scale
#pragma unroll
  for (int oo = 0; oo < 8; ++oo) {
    const int o = o0 + ob + oo;
    const float sc = scale[o];
    const int* wrow = wq + (size_t)o * K_DIM + i0 + ib;
    int4 w0 = *(const int4*)wrow;
    int4 w1 = *(const int4*)(wrow + 4);
    acc[oo][0] = (float)w0.x * sc; acc[oo][1] = (float)w0.y * sc;
    acc[oo][2] = (float)w0.z * sc; acc[oo][3] = (float)w0.w * sc;
    acc[oo][4] = (float)w1.x * sc; acc[oo][5] = (float)w1.y * sc;
    acc[oo][6] = (float)w1.z * sc; acc[oo][7] = (float)w1.w * sc;
  }

  // rank accumulation: per r, 2x ds_read_b128 (B) + 8 broadcast b32 (A) + 64 FMA
  for (int r = 0; r < RANK_; ++r) {
    float4 b0 = *(const float4*)&sB[r][ib];
    float4 b1 = *(const float4*)&sB[r][ib + 4];
#pragma unroll
    for (int oo = 0; oo < 8; ++oo) {
      const float a = sA[ob + oo][r];
      acc[oo][0] += a * b0.x; acc[oo][1] += a * b0.y;
      acc[oo][2] += a * b0.z; acc[oo][3] += a * b0.w;
      acc[oo][4] += a * b1.x; acc[oo][5] += a * b1.y;
      acc[oo][6] += a * b1.z; acc[oo][7] += a * b1.w;
    }
  }

  // store bf16, 16B per o-row per thread, coalesced across ith
#pragma unroll
  for (int oo = 0; oo < 8; ++oo) {
    ushort8 pk;
#pragma unroll
    for (int ii = 0; ii < 8; ++ii) pk[ii] = f2bf(acc[oo][ii]);
    *(ushort8*)&weff[(size_t)(o0 + ob + oo) * K_DIM + i0 + ib] = pk;
  }
}

// ---- Kernel 3: 256x256 8-phase bf16 GEMM (T1+T2+T3/T4+T5) — FROZEN from round 3 ----
// 188 µs, MfmaUtil 35% (47% per-round, 1.5-pass tail), bank conflicts 0.
#define MF(A,B,C) __builtin_amdgcn_mfma_f32_16x16x32_bf16(A, B, C, 0, 0, 0)
#define MFMA16(MB) do { \
  acc[MB+0][0]=MF(a0,b0,acc[MB+0][0]); acc[MB+0][1]=MF(a0,b1,acc[MB+0][1]); \
  acc[MB+0][2]=MF(a0,b2,acc[MB+0][2]); acc[MB+0][3]=MF(a0,b3,acc[MB+0][3]); \
  acc[MB+1][0]=MF(a1,b0,acc[MB+1][0]); acc[MB+1][1]=MF(a1,b1,acc[MB+1][1]); \
  acc[MB+1][2]=MF(a1,b2,acc[MB+1][2]); acc[MB+1][3]=MF(a1,b3,acc[MB+1][3]); \
  acc[MB+2][0]=MF(a2,b0,acc[MB+2][0]); acc[MB+2][1]=MF(a2,b1,acc[MB+2][1]); \
  acc[MB+2][2]=MF(a2,b2,acc[MB+2][2]); acc[MB+2][3]=MF(a2,b3,acc[MB+2][3]); \
  acc[MB+3][0]=MF(a3,b0,acc[MB+3][0]); acc[MB+3][1]=MF(a3,b1,acc[MB+3][1]); \
  acc[MB+3][2]=MF(a3,b2,acc[MB+3][2]); acc[MB+3][3]=MF(a3,b3,acc[MB+3][3]); \
} while (0)

__global__ __launch_bounds__(512, 2) void gemm8_kernel(
    const unsigned short* __restrict__ xb, const unsigned short* __restrict__ weff,
    const float* __restrict__ bias, float* __restrict__ out) {
  extern __shared__ unsigned short smem[];  // 65536 ushorts = 128 KiB

  const int tid = threadIdx.x;
  const int lane = tid & 63;
  const int wid = tid >> 6;     // 0..7
  const int wm = wid >> 2;      // 0..1  (M)
  const int wn = wid & 3;       // 0..3  (N)

  // XCD-aware bijective swizzle (384 % 8 == 0)
  const int bid = blockIdx.x;
  const int swz = (bid & 7) * 48 + (bid >> 3);
  const int tileM = swz / (N_DIM / BN);
  const int tileN = swz % (N_DIM / BN);
  const int rowA0 = tileM * BM;
  const int colB0 = tileN * BN;

  const int srow = tid >> 3;
  const int skidx = ((tid & 7) * 8) ^ ((srow & 7) << 3);
  const unsigned short* gAbase = xb + (size_t)(rowA0 + srow) * K_DIM + skidx;
  const unsigned short* gBbase = weff + (size_t)(colB0 + srow) * K_DIM + skidx;
  const int ldsLin = tid * 8;

#define ABASE(b) ((b) * 32768)
#define BBASE(b) ((b) * 32768 + 16384)

  auto stageA = [&](int t) {
    const int b = t & 1;
    const unsigned short* g = gAbase + (size_t)t * BK;
#pragma unroll
    for (int l = 0; l < 4; ++l)
      __builtin_amdgcn_global_load_lds(
          (const __attribute__((address_space(1))) void*)(g + (size_t)l * 64 * K_DIM),
          (__attribute__((address_space(3))) void*)&smem[ABASE(b) + l * 4096 + ldsLin], 16, 0, 0);
  };
  auto stageB = [&](int t) {
    const int b = t & 1;
    const unsigned short* g = gBbase + (size_t)t * BK;
#pragma unroll
    for (int l = 0; l < 4; ++l)
      __builtin_amdgcn_global_load_lds(
          (const __attribute__((address_space(1))) void*)(g + (size_t)l * 64 * K_DIM),
          (__attribute__((address_space(3))) void*)&smem[BBASE(b) + l * 4096 + ldsLin], 16, 0, 0);
  };

  const int lrow = lane & 15;
  const int khalf = lane >> 4;             // 0..3
  const int rsw = (lrow & 7) << 3;
  auto ldA = [&](int b, int mf, int kk) -> bf16x8 {
    return *(const bf16x8*)&smem[ABASE(b) + (wm * 128 + mf * 16 + lrow) * 64 +
                                 ((kk * 32 + khalf * 8) ^ rsw)];
  };
  auto ldB = [&](int b, int nf, int kk) -> bf16x8 {
    return *(const bf16x8*)&smem[BBASE(b) + (wn * 64 + nf * 16 + lrow) * 64 +
                                 ((kk * 32 + khalf * 8) ^ rsw)];
  };

  floatx4 acc[8][4];
#pragma unroll
  for (int m = 0; m < 8; ++m)
#pragma unroll
    for (int n = 0; n < 4; ++n)
      acc[m][n] = (floatx4){0.f, 0.f, 0.f, 0.f};

  stageB(0); stageA(0); stageB(1);
  asm volatile("s_waitcnt vmcnt(4)" ::: "memory");
  __builtin_amdgcn_s_barrier();

  bf16x8 a0, a1, a2, a3, b0, b1, b2, b3;
#pragma unroll 2
  for (int g = 0; g < NT; ++g) {
    const int bf = g & 1;
    // ---- phase 1
    a0 = ldA(bf, 0, 0); a1 = ldA(bf, 1, 0); a2 = ldA(bf, 2, 0); a3 = ldA(bf, 3, 0);
    b0 = ldB(bf, 0, 0); b1 = ldB(bf, 1, 0); b2 = ldB(bf, 2, 0); b3 = ldB(bf, 3, 0);
    if (g + 1 < NT) stageA(g + 1);
    __builtin_amdgcn_s_barrier();
    asm volatile("s_waitcnt lgkmcnt(0)" ::: "memory");
    __builtin_amdgcn_s_setprio(1);
    MFMA16(0);
    __builtin_amdgcn_s_setprio(0);
    __builtin_amdgcn_s_barrier();
    // ---- phase 2 (B regs reused)
    a0 = ldA(bf, 4, 0); a1 = ldA(bf, 5, 0); a2 = ldA(bf, 6, 0); a3 = ldA(bf, 7, 0);
    __builtin_amdgcn_s_barrier();
    asm volatile("s_waitcnt lgkmcnt(0)" ::: "memory");
    __builtin_amdgcn_s_setprio(1);
    MFMA16(4);
    __builtin_amdgcn_s_setprio(0);
    __builtin_amdgcn_s_barrier();
    // ---- phase 3
    a0 = ldA(bf, 0, 1); a1 = ldA(bf, 1, 1); a2 = ldA(bf, 2, 1); a3 = ldA(bf, 3, 1);
    b0 = ldB(bf, 0, 1); b1 = ldB(bf, 1, 1); b2 = ldB(bf, 2, 1); b3 = ldB(bf, 3, 1);
    __builtin_amdgcn_s_barrier();
    asm volatile("s_waitcnt lgkmcnt(0)" ::: "memory");
    __builtin_amdgcn_s_setprio(1);
    MFMA16(0);
    __builtin_amdgcn_s_setprio(0);
    __builtin_amdgcn_s_barrier();
    // ---- phase 4 + gate
    a0 = ldA(bf, 4, 1); a1 = ldA(bf, 5, 1); a2 = ldA(bf, 6, 1); a3 = ldA(bf, 7, 1);
    if (g + 2 < NT) stageB(g + 2);
    __builtin_amdgcn_s_barrier();
    asm volatile("s_waitcnt lgkmcnt(0)" ::: "memory");
    __builtin_amdgcn_s_setprio(1);
    MFMA16(4);
    __builtin_amdgcn_s_setprio(0);
    if (g < NT - 2) asm volatile("s_waitcnt vmcnt(4)" ::: "memory");
    else            asm volatile("s_waitcnt vmcnt(0)" ::: "memory");
    __builtin_amdgcn_s_barrier();
  }

  // epilogue: C/D layout col=lane&15, row=(lane>>4)*4+j (m89-verified); fuse bias
  const int orow0 = rowA0 + wm * 128;
  const int ocol0 = colB0 + wn * 64;
#pragma unroll
  for (int nf = 0; nf < 4; ++nf) {
    const int col = ocol0 + nf * 16 + lrow;
    const float bvs = bias[col];
#pragma unroll
    for (int mf = 0; mf < 8; ++mf) {
      const int r0 = orow0 + mf * 16 + khalf * 4;
#pragma unroll
      for (int j = 0; j < 4; ++j)
        out[(size_t)(r0 + j) * N_DIM + col] = acc[mf][nf][j] + bvs;
    }
  }
}

extern "C" void kernel_launch(void* const* d_in, const int* in_sizes, int n_in,
                              void* d_out, int out_size, void* d_ws, size_t ws_size,
                              hipStream_t stream) {
  const float* x = (const float*)d_in[0];
  const int* wq = (const int*)d_in[1];
  const float* scale = (const float*)d_in[2];
  const float* lA = (const float*)d_in[3];
  const float* lB = (const float*)d_in[4];
  const float* bias = (const float*)d_in[5];
  float* out = (float*)d_out;

  unsigned short* xb = (unsigned short*)d_ws;           // 8192*3072 bf16 = 50.3 MB
  unsigned short* weff = xb + (size_t)M_DIM * K_DIM;    // 3072*3072 bf16 = 18.9 MB

  hipFuncSetAttribute((const void*)gemm8_kernel,
                      hipFuncAttributeMaxDynamicSharedMemorySize, 131072);

  cvt_x_kernel<<<(M_DIM * (size_t)K_DIM) / (8 * 256), 256, 0, stream>>>(x, xb);
  build_weff_kernel<<<dim3(K_DIM / 128, N_DIM / 128), 256, 0, stream>>>(wq, scale, lA, lB, weff);
  gemm8_kernel<<<(M_DIM / BM) * (N_DIM / BN), 512, 131072, stream>>>(xb, weff, bias, out);
}

// Round 6
// 354.744 us; speedup vs baseline: 1.4092x; 1.0804x over previous
//
#include <hip/hip_runtime.h>
#include <hip/hip_bf16.h>

#define M_DIM 8192
#define N_DIM 3072
#define K_DIM 3072
#define RANK_ 64

#define BM 256
#define BN 192
#define BK 64
#define NT (K_DIM / BK)   // 48 K-tiles

typedef __attribute__((ext_vector_type(8))) __bf16 bf16x8;
typedef __attribute__((ext_vector_type(4))) float floatx4;
typedef __attribute__((ext_vector_type(8))) unsigned short ushort8;

__device__ __forceinline__ unsigned short f2bf(float f) {
  union { float f; unsigned u; } v;
  v.f = f;
  return (unsigned short)((v.u + 0x7fffu + ((v.u >> 16) & 1u)) >> 16);
}

// ---- Kernel 1: x fp32 -> bf16 (memory-bound, vectorized) ----
__global__ void cvt_x_kernel(const float* __restrict__ x, unsigned short* __restrict__ xb) {
  size_t i = ((size_t)blockIdx.x * 256u + threadIdx.x) * 8u;
  const float4* xp = (const float4*)(x + i);
  float4 a = xp[0];
  float4 b = xp[1];
  ushort8 r;
  r[0] = f2bf(a.x); r[1] = f2bf(a.y); r[2] = f2bf(a.z); r[3] = f2bf(a.w);
  r[4] = f2bf(b.x); r[5] = f2bf(b.y); r[6] = f2bf(b.z); r[7] = f2bf(b.w);
  *(ushort8*)(xb + i) = r;
}

// ---- Kernel 2 v3 (frozen, i0 store-bug FIXED): W_eff = Wq*scale + A@B ----
__global__ __launch_bounds__(256) void build_weff_kernel(
    const int* __restrict__ wq, const float* __restrict__ scale,
    const float* __restrict__ lA, const float* __restrict__ lB,
    unsigned short* __restrict__ weff) {
  __shared__ float sB[64][128];
  __shared__ float sA[128][65];

  const int tid = threadIdx.x;
  const int i0 = blockIdx.x * 128;
  const int o0 = blockIdx.y * 128;

#pragma unroll
  for (int l = 0; l < 8; ++l) {
    int lin = l * 256 + tid;
    int r = lin >> 5;
    int c4 = (lin & 31) * 4;
    *(float4*)&sB[r][c4] = *(const float4*)&lB[(size_t)r * K_DIM + i0 + c4];
  }
#pragma unroll
  for (int l = 0; l < 8; ++l) {
    int lin = l * 256 + tid;
    int o = lin >> 4;
    int c4 = (lin & 15) * 4;
    *(float4*)&sA[o][c4] = *(const float4*)&lA[(size_t)(o0 + o) * RANK_ + c4];
  }
  __syncthreads();

  const int ib = (tid & 15) * 8;
  const int ob = (tid >> 4) * 8;

  float acc[8][8];
#pragma unroll
  for (int oo = 0; oo < 8; ++oo) {
    const int o = o0 + ob + oo;
    const float sc = scale[o];
    const int* wrow = wq + (size_t)o * K_DIM + i0 + ib;
    int4 w0 = *(const int4*)wrow;
    int4 w1 = *(const int4*)(wrow + 4);
    acc[oo][0] = (float)w0.x * sc; acc[oo][1] = (float)w0.y * sc;
    acc[oo][2] = (float)w0.z * sc; acc[oo][3] = (float)w0.w * sc;
    acc[oo][4] = (float)w1.x * sc; acc[oo][5] = (float)w1.y * sc;
    acc[oo][6] = (float)w1.z * sc; acc[oo][7] = (float)w1.w * sc;
  }

  for (int r = 0; r < RANK_; ++r) {
    float4 b0 = *(const float4*)&sB[r][ib];
    float4 b1 = *(const float4*)&sB[r][ib + 4];
#pragma unroll
    for (int oo = 0; oo < 8; ++oo) {
      const float a = sA[ob + oo][r];
      acc[oo][0] += a * b0.x; acc[oo][1] += a * b0.y;
      acc[oo][2] += a * b0.z; acc[oo][3] += a * b0.w;
      acc[oo][4] += a * b1.x; acc[oo][5] += a * b1.y;
      acc[oo][6] += a * b1.z; acc[oo][7] += a * b1.w;
    }
  }

#pragma unroll
  for (int oo = 0; oo < 8; ++oo) {
    ushort8 pk;
#pragma unroll
    for (int ii = 0; ii < 8; ++ii) pk[ii] = f2bf(acc[oo][ii]);
    *(ushort8*)&weff[(size_t)(o0 + ob + oo) * K_DIM + i0 + ib] = pk;
  }
}

// ---- Kernel 3: 256x192 8-wave bf16 GEMM, grid 512 = 2 exact passes ----
// 8 waves (2M x 4N) -> wave tile 128x48. acc[8][3] (96 AGPR).
// LDS 112 KiB: A dbuf 2x32KB @0, B dbuf 2x24KB @32768 ushorts.
// Staging spread: ph1/ph2 each 2 A-chunks(g+1); ph4: 3 B-chunks(g+2) + vmcnt(3).
// WAR-safe: A(g+1) target region last read ph4(g-1) (drained); B(g) reads end ph3.
#define MF(A,B,C) __builtin_amdgcn_mfma_f32_16x16x32_bf16(A, B, C, 0, 0, 0)
#define MFMA12(MB) do { \
  acc[MB+0][0]=MF(a0,b0,acc[MB+0][0]); acc[MB+0][1]=MF(a0,b1,acc[MB+0][1]); acc[MB+0][2]=MF(a0,b2,acc[MB+0][2]); \
  acc[MB+1][0]=MF(a1,b0,acc[MB+1][0]); acc[MB+1][1]=MF(a1,b1,acc[MB+1][1]); acc[MB+1][2]=MF(a1,b2,acc[MB+1][2]); \
  acc[MB+2][0]=MF(a2,b0,acc[MB+2][0]); acc[MB+2][1]=MF(a2,b1,acc[MB+2][1]); acc[MB+2][2]=MF(a2,b2,acc[MB+2][2]); \
  acc[MB+3][0]=MF(a3,b0,acc[MB+3][0]); acc[MB+3][1]=MF(a3,b1,acc[MB+3][1]); acc[MB+3][2]=MF(a3,b2,acc[MB+3][2]); \
} while (0)

#define ABASE(b) ((b) * 16384)
#define BBASE(b) (32768 + (b) * 12288)

__global__ __launch_bounds__(512, 2) void gemm8_kernel(
    const unsigned short* __restrict__ xb, const unsigned short* __restrict__ weff,
    const float* __restrict__ bias, float* __restrict__ out) {
  extern __shared__ unsigned short smem[];  // 57344 ushorts = 112 KiB

  const int tid = threadIdx.x;
  const int lane = tid & 63;
  const int wid = tid >> 6;     // 0..7
  const int wm = wid >> 2;      // 0..1  (M)
  const int wn = wid & 3;       // 0..3  (N)

  // XCD-aware bijective swizzle (512 % 8 == 0, cpx = 64)
  const int bid = blockIdx.x;
  const int swz = (bid & 7) * 64 + (bid >> 3);
  const int tileM = swz / (N_DIM / BN);   // /16
  const int tileN = swz % (N_DIM / BN);
  const int rowA0 = tileM * BM;
  const int colB0 = tileN * BN;

  const int srow = tid >> 3;
  const int skidx = ((tid & 7) * 8) ^ ((srow & 7) << 3);
  const unsigned short* gAbase = xb + (size_t)(rowA0 + srow) * K_DIM + skidx;
  const unsigned short* gBbase = weff + (size_t)(colB0 + srow) * K_DIM + skidx;
  const int ldsLin = tid * 8;

  // A chunks: 4 x (64 rows); issue half at a time
  auto stageA2 = [&](int t, int h) {
    const int b = t & 1;
    const unsigned short* g = gAbase + (size_t)t * BK;
#pragma unroll
    for (int l = h * 2; l < h * 2 + 2; ++l)
      __builtin_amdgcn_global_load_lds(
          (const __attribute__((address_space(1))) void*)(g + (size_t)l * 64 * K_DIM),
          (__attribute__((address_space(3))) void*)&smem[ABASE(b) + l * 4096 + ldsLin], 16, 0, 0);
  };
  // B chunks: 3 x (64 rows)
  auto stageB = [&](int t) {
    const int b = t & 1;
    const unsigned short* g = gBbase + (size_t)t * BK;
#pragma unroll
    for (int l = 0; l < 3; ++l)
      __builtin_amdgcn_global_load_lds(
          (const __attribute__((address_space(1))) void*)(g + (size_t)l * 64 * K_DIM),
          (__attribute__((address_space(3))) void*)&smem[BBASE(b) + l * 4096 + ldsLin], 16, 0, 0);
  };

  const int lrow = lane & 15;
  const int khalf = lane >> 4;             // 0..3
  const int rsw = (lrow & 7) << 3;
  auto ldA = [&](int b, int mf, int kk) -> bf16x8 {
    return *(const bf16x8*)&smem[ABASE(b) + (wm * 128 + mf * 16 + lrow) * 64 +
                                 ((kk * 32 + khalf * 8) ^ rsw)];
  };
  auto ldB = [&](int b, int nf, int kk) -> bf16x8 {
    return *(const bf16x8*)&smem[BBASE(b) + (wn * 48 + nf * 16 + lrow) * 64 +
                                 ((kk * 32 + khalf * 8) ^ rsw)];
  };

  floatx4 acc[8][3];
#pragma unroll
  for (int m = 0; m < 8; ++m)
#pragma unroll
    for (int n = 0; n < 3; ++n)
      acc[m][n] = (floatx4){0.f, 0.f, 0.f, 0.f};

  // prologue: B(0):3, A(0):4, B(1):3 staged; gate tile 0 -> vmcnt(3)
  stageB(0); stageA2(0, 0); stageA2(0, 1); stageB(1);
  asm volatile("s_waitcnt vmcnt(3)" ::: "memory");
  __builtin_amdgcn_s_barrier();

  bf16x8 a0, a1, a2, a3, b0, b1, b2;
#pragma unroll 2
  for (int g = 0; g < NT; ++g) {
    const int bf = g & 1;
    // ---- phase 1: A(m0-3,kk0) + B(kk0); stage A(g+1) half 0
    a0 = ldA(bf, 0, 0); a1 = ldA(bf, 1, 0); a2 = ldA(bf, 2, 0); a3 = ldA(bf, 3, 0);
    b0 = ldB(bf, 0, 0); b1 = ldB(bf, 1, 0); b2 = ldB(bf, 2, 0);
    if (g + 1 < NT) stageA2(g + 1, 0);
    __builtin_amdgcn_s_barrier();
    asm volatile("s_waitcnt lgkmcnt(0)" ::: "memory");
    __builtin_amdgcn_s_setprio(1);
    MFMA12(0);
    __builtin_amdgcn_s_setprio(0);
    __builtin_amdgcn_s_barrier();
    // ---- phase 2: A(m4-7,kk0); stage A(g+1) half 1
    a0 = ldA(bf, 4, 0); a1 = ldA(bf, 5, 0); a2 = ldA(bf, 6, 0); a3 = ldA(bf, 7, 0);
    if (g + 1 < NT) stageA2(g + 1, 1);
    __builtin_amdgcn_s_barrier();
    asm volatile("s_waitcnt lgkmcnt(0)" ::: "memory");
    __builtin_amdgcn_s_setprio(1);
    MFMA12(4);
    __builtin_amdgcn_s_setprio(0);
    __builtin_amdgcn_s_barrier();
    // ---- phase 3: A(m0-3,kk1) + B(kk1)
    a0 = ldA(bf, 0, 1); a1 = ldA(bf, 1, 1); a2 = ldA(bf, 2, 1); a3 = ldA(bf, 3, 1);
    b0 = ldB(bf, 0, 1); b1 = ldB(bf, 1, 1); b2 = ldB(bf, 2, 1);
    __builtin_amdgcn_s_barrier();
    asm volatile("s_waitcnt lgkmcnt(0)" ::: "memory");
    __builtin_amdgcn_s_setprio(1);
    MFMA12(0);
    __builtin_amdgcn_s_setprio(0);
    __builtin_amdgcn_s_barrier();
    // ---- phase 4: A(m4-7,kk1); stage B(g+2); gate
    a0 = ldA(bf, 4, 1); a1 = ldA(bf, 5, 1); a2 = ldA(bf, 6, 1); a3 = ldA(bf, 7, 1);
    if (g + 2 < NT) stageB(g + 2);
    __builtin_amdgcn_s_barrier();
    asm volatile("s_waitcnt lgkmcnt(0)" ::: "memory");
    __builtin_amdgcn_s_setprio(1);
    MFMA12(4);
    __builtin_amdgcn_s_setprio(0);
    if (g < NT - 2) asm volatile("s_waitcnt vmcnt(3)" ::: "memory");
    else            asm volatile("s_waitcnt vmcnt(0)" ::: "memory");
    __builtin_amdgcn_s_barrier();
  }

  // epilogue: C/D layout col=lane&15, row=(lane>>4)*4+j (m89-verified); fuse bias
  const int orow0 = rowA0 + wm * 128;
  const int ocol0 = colB0 + wn * 48;
#pragma unroll
  for (int nf = 0; nf < 3; ++nf) {
    const int col = ocol0 + nf * 16 + lrow;
    const float bvs = bias[col];
#pragma unroll
    for (int mf = 0; mf < 8; ++mf) {
      const int r0 = orow0 + mf * 16 + khalf * 4;
#pragma unroll
      for (int j = 0; j < 4; ++j)
        out[(size_t)(r0 + j) * N_DIM + col] = acc[mf][nf][j] + bvs;
    }
  }
}

extern "C" void kernel_launch(void* const* d_in, const int* in_sizes, int n_in,
                              void* d_out, int out_size, void* d_ws, size_t ws_size,
                              hipStream_t stream) {
  const float* x = (const float*)d_in[0];
  const int* wq = (const int*)d_in[1];
  const float* scale = (const float*)d_in[2];
  const float* lA = (const float*)d_in[3];
  const float* lB = (const float*)d_in[4];
  const float* bias = (const float*)d_in[5];
  float* out = (float*)d_out;

  unsigned short* xb = (unsigned short*)d_ws;           // 8192*3072 bf16 = 50.3 MB
  unsigned short* weff = xb + (size_t)M_DIM * K_DIM;    // 3072*3072 bf16 = 18.9 MB

  hipFuncSetAttribute((const void*)gemm8_kernel,
                      hipFuncAttributeMaxDynamicSharedMemorySize, 114688);

  cvt_x_kernel<<<(M_DIM * (size_t)K_DIM) / (8 * 256), 256, 0, stream>>>(x, xb);
  build_weff_kernel<<<dim3(K_DIM / 128, N_DIM / 128), 256, 0, stream>>>(wq, scale, lA, lB, weff);
  gemm8_kernel<<<(M_DIM / BM) * (N_DIM / BN), 512, 114688, stream>>>(xb, weff, bias, out);
}